// Round 1
// baseline (76925.513 us; speedup 1.0000x reference)
//
#include <hip/hip_runtime.h>
#include <math.h>

// ---------------- problem constants ----------------
#define TS   2048   // timesteps
#define NN   100    // nodes
#define NP   112    // padded nodes (7*16)
#define FD   128    // input features
#define HD   512    // hidden
#define G3   1536   // 3*HD
#define GRPS 7      // node groups of 16
#define SLC  32     // hidden slices per group (16 units each)
#define KNN  8
#define GIN  704    // HD + 64 + 128
#define GH   256
#define GOUT 128

__device__ __forceinline__ float sigmoidf_(float v) { return 1.f / (1.f + __expf(-v)); }

// =====================================================================
// Persistent GRU. Grid = GRPS*SLC = 224 blocks, 256 threads.
// block (g,s): nodes [g*16, g*16+16), hidden units [s*16, s*16+16).
// thread: i = tid&15 (node), jj = tid>>4 (unit). One (i,j) pair each.
// Per step: stage x_t-tile + h-tile in LDS, dot K=640 with Wih/Whh rows
// streamed from L2, gate update, write h to ping-pong buffer, per-group
// device-scope barrier (sense via monotone step flag).
// =====================================================================
__global__ __launch_bounds__(256, 1) void gru_kernel(
    const float* __restrict__ x,     // [TS, NN, FD]
    const float* __restrict__ Wih,   // [G3, FD]
    const float* __restrict__ Whh,   // [G3, HD]
    const float* __restrict__ bih,   // [G3]
    const float* __restrict__ bhh,   // [G3]
    float* __restrict__ h0buf,       // [NP, HD]  zero-initialized (h0)
    float* __restrict__ h1buf,       // [NP, HD]
    int*   __restrict__ bar)         // [GRPS][64] zero-initialized
{
    const int wg  = blockIdx.x;
    const int g   = wg / SLC;
    const int s   = wg % SLC;
    const int tid = threadIdx.x;
    const int i   = tid & 15;
    const int jj  = tid >> 4;
    const int nb  = g * 16;
    const int c   = s * 16 + jj;          // hidden column 0..511

    __shared__ __align__(16) float Ax[16][132];   // stride 132: banks 4*i -> 2-way (free)
    __shared__ __align__(16) float Ah[16][516];   // stride 516: banks 4*i

    const float* wr_x = Wih + (size_t)c * FD;
    const float* wz_x = Wih + (size_t)(HD + c) * FD;
    const float* wn_x = Wih + (size_t)(2 * HD + c) * FD;
    const float* wr_h = Whh + (size_t)c * HD;
    const float* wz_h = Whh + (size_t)(HD + c) * HD;
    const float* wn_h = Whh + (size_t)(2 * HD + c) * HD;
    const float br  = bih[c] + bhh[c];
    const float bz  = bih[HD + c] + bhh[HD + c];
    const float bnx = bih[2 * HD + c];
    const float bnh = bhh[2 * HD + c];

    int* cntp  = bar + g * 64;
    int* flagp = bar + g * 64 + 32;

    for (int t = 0; t < TS; ++t) {
        const float* hcur = (t & 1) ? h1buf : h0buf;
        float*       hnxt = (t & 1) ? h0buf : h1buf;

        // ---- stage A = [x_t | h] for this node tile ----
        {
            const float* xt = x + (size_t)t * NN * FD;
            #pragma unroll
            for (int q = 0; q < 2; ++q) {            // 16x128 = 512 float4
                int v   = tid + q * 256;
                int row = v >> 5;
                int fc  = (v & 31) << 2;
                float4 val = make_float4(0.f, 0.f, 0.f, 0.f);
                int node = nb + row;
                if (node < NN)
                    val = *(const float4*)(xt + (size_t)node * FD + fc);
                *(float4*)&Ax[row][fc] = val;
            }
            #pragma unroll
            for (int q = 0; q < 8; ++q) {            // 16x512 = 2048 float4
                int v   = tid + q * 256;
                int row = v >> 7;
                int kc  = (v & 127) << 2;
                float4 val = *(const float4*)(hcur + (size_t)(nb + row) * HD + kc);
                *(float4*)&Ah[row][kc] = val;
            }
        }
        __syncthreads();

        // ---- K=640 dot products (x part K=128, h part K=512) ----
        float accr = 0.f, accz = 0.f, accnx = 0.f, accnh = 0.f;
        {
            const float4* a4 = (const float4*)&Ax[i][0];
            #pragma unroll 4
            for (int k4 = 0; k4 < FD / 4; ++k4) {
                float4 a  = a4[k4];
                float4 r4 = ((const float4*)wr_x)[k4];
                float4 z4 = ((const float4*)wz_x)[k4];
                float4 n4 = ((const float4*)wn_x)[k4];
                accr  = fmaf(a.w, r4.w, fmaf(a.z, r4.z, fmaf(a.y, r4.y, fmaf(a.x, r4.x, accr))));
                accz  = fmaf(a.w, z4.w, fmaf(a.z, z4.z, fmaf(a.y, z4.y, fmaf(a.x, z4.x, accz))));
                accnx = fmaf(a.w, n4.w, fmaf(a.z, n4.z, fmaf(a.y, n4.y, fmaf(a.x, n4.x, accnx))));
            }
        }
        {
            const float4* a4 = (const float4*)&Ah[i][0];
            #pragma unroll 4
            for (int k4 = 0; k4 < HD / 4; ++k4) {
                float4 a  = a4[k4];
                float4 r4 = ((const float4*)wr_h)[k4];
                float4 z4 = ((const float4*)wz_h)[k4];
                float4 n4 = ((const float4*)wn_h)[k4];
                accr  = fmaf(a.w, r4.w, fmaf(a.z, r4.z, fmaf(a.y, r4.y, fmaf(a.x, r4.x, accr))));
                accz  = fmaf(a.w, z4.w, fmaf(a.z, z4.z, fmaf(a.y, z4.y, fmaf(a.x, z4.x, accz))));
                accnh = fmaf(a.w, n4.w, fmaf(a.z, n4.z, fmaf(a.y, n4.y, fmaf(a.x, n4.x, accnh))));
            }
        }

        // ---- gates + h update (torch GRU: r,z,n order) ----
        float r    = sigmoidf_(accr + br);
        float z    = sigmoidf_(accz + bz);
        float n    = tanhf(accnx + bnx + r * (accnh + bnh));
        float hold = Ah[i][c];
        float hnew = (1.f - z) * n + z * hold;
        hnxt[(size_t)(nb + i) * HD + c] = hnew;

        // ---- per-group barrier (device scope: h crosses XCDs) ----
        __syncthreads();   // drains this WG's h stores to L2 (vmcnt(0) before s_barrier)
        if (tid == 0) {
            __threadfence();   // wb: publish h at agent scope
            int old = __hip_atomic_fetch_add(cntp, 1, __ATOMIC_ACQ_REL, __HIP_MEMORY_SCOPE_AGENT);
            if (old == SLC - 1) {
                __hip_atomic_store(cntp, 0, __ATOMIC_RELAXED, __HIP_MEMORY_SCOPE_AGENT);
                __hip_atomic_store(flagp, t + 1, __ATOMIC_RELEASE, __HIP_MEMORY_SCOPE_AGENT);
            } else {
                int f;
                do {
                    __builtin_amdgcn_s_sleep(1);
                    f = __hip_atomic_load(flagp, __ATOMIC_ACQUIRE, __HIP_MEMORY_SCOPE_AGENT);
                } while (f < t + 1);
            }
            __threadfence();   // inv: drop stale h lines before next staging
        }
        __syncthreads();
    }
}

// ===================== epilogue (tiny) =====================

// gnn_in = [enc(512) | flat@flat_W.T+b (64) | emb(128)] ; grid NN x 128
__global__ void e1_gnn_in(const float* __restrict__ enc, const float* __restrict__ flat,
                          const float* __restrict__ emb, const float* __restrict__ fW,
                          const float* __restrict__ fb, float* __restrict__ gnn)
{
    int i = blockIdx.x, tid = threadIdx.x;
    const float4* src = (const float4*)(enc + (size_t)i * HD);
    float4* dst = (float4*)(gnn + (size_t)i * GIN);
    dst[tid] = src[tid];                                   // 128*4 = 512 floats
    if (tid < 64) {
        float acc = fb[tid];
        const float* w  = fW + tid * 32;
        const float* fl = flat + i * 32;
        #pragma unroll
        for (int k = 0; k < 32; ++k) acc = fmaf(fl[k], w[k], acc);
        gnn[(size_t)i * GIN + HD + tid] = acc;
    }
    gnn[(size_t)i * GIN + HD + 64 + tid] = emb[(size_t)i * FD + tid];
}

// row norms (clamped) ; 1 x 128
__global__ void e2a_norm(const float* __restrict__ emb, float* __restrict__ mx)
{
    int j = threadIdx.x;
    if (j < NN) {
        float acc = 0.f;
        const float* e = emb + (size_t)j * FD;
        for (int d = 0; d < FD; ++d) acc = fmaf(e[d], e[d], acc);
        mx[j] = fmaxf(sqrtf(acc), 1e-8f);
    }
}

// cosine sim row + zero diag + top-8 (stable: strict > keeps lowest idx, like lax.top_k)
__global__ void e2b_knn(const float* __restrict__ emb, const float* __restrict__ mx,
                        int* __restrict__ tgt)
{
    int i = blockIdx.x, tid = threadIdx.x;   // 128 threads
    __shared__ float ei[FD];
    __shared__ float srow[NN];
    ei[tid] = emb[(size_t)i * FD + tid];
    __syncthreads();
    if (tid < NN) {
        float acc = 0.f;
        const float* e = emb + (size_t)tid * FD;
        for (int d = 0; d < FD; ++d) acc = fmaf(ei[d], e[d], acc);
        float sim = acc / (mx[i] * mx[tid]);
        srow[tid] = (tid == i) ? 0.f : sim;
    }
    __syncthreads();
    if (tid == 0) {
        for (int t = 0; t < KNN; ++t) {
            float best = -1e30f; int bi = 0;
            for (int j = 0; j < NN; ++j) { float v = srow[j]; if (v > best) { best = v; bi = j; } }
            srow[bi] = -1e30f;
            tgt[i * KNN + t] = bi;
        }
    }
}

// scatter aggregation: agg[tgt[e]] += xin[e>>3], cnt[tgt[e]] += 1 ; grid NN*KNN
__global__ void e3_agg(const float* __restrict__ xin, const int* __restrict__ tgt,
                       float* __restrict__ agg, float* __restrict__ cnt, int D)
{
    int e = blockIdx.x, src = e >> 3, tg = tgt[e];
    for (int d = threadIdx.x; d < D; d += blockDim.x)
        atomicAdd(&agg[(size_t)tg * D + d], xin[(size_t)src * D + d]);
    if (threadIdx.x == 0) atomicAdd(&cnt[tg], 1.0f);
}

// SAGE linear: out = [relu]( (agg/max(cnt,1))@Wl.T + xin@Wr.T + b ) ; grid NN x Dout
__global__ void e4_sage(const float* __restrict__ agg, const float* __restrict__ xin,
                        const float* __restrict__ cnt,
                        const float* __restrict__ Wl, const float* __restrict__ Wr,
                        const float* __restrict__ b, float* __restrict__ out,
                        int Din, int Dout, int dorelu)
{
    int j = blockIdx.x, o = threadIdx.x;     // blockDim == Dout
    extern __shared__ float sm[];
    float* la = sm;
    float* lx = sm + Din;
    for (int d = o; d < Din; d += blockDim.x) {
        la[d] = agg[(size_t)j * Din + d];
        lx[d] = xin[(size_t)j * Din + d];
    }
    __syncthreads();
    float inv = 1.f / fmaxf(cnt[j], 1.f);
    float acc1 = 0.f, acc2 = 0.f;
    const float* wl = Wl + (size_t)o * Din;
    const float* wr = Wr + (size_t)o * Din;
    for (int k = 0; k < Din; ++k) {
        acc1 = fmaf(la[k], wl[k], acc1);
        acc2 = fmaf(lx[k], wr[k], acc2);
    }
    float v = fmaf(acc1, inv, acc2) + b[o];
    if (dorelu) v = fmaxf(v, 0.f);
    out[(size_t)j * Dout + o] = v;
}

// out = sigmoid([g | enc] @ out_W.T + b) ; 1 x 128
__global__ void e7_out(const float* __restrict__ g, const float* __restrict__ enc,
                       const float* __restrict__ oW, const float* __restrict__ ob,
                       float* __restrict__ out)
{
    int j = threadIdx.x;
    if (j < NN) {
        float acc = ob[0];
        const float* gr = g + (size_t)j * GOUT;
        for (int d = 0; d < GOUT; ++d) acc = fmaf(gr[d], oW[d], acc);
        const float* er = enc + (size_t)j * HD;
        for (int d = 0; d < HD; ++d) acc = fmaf(er[d], oW[GOUT + d], acc);
        out[j] = 1.f / (1.f + expf(-acc));
    }
}

// ===================== launch =====================
extern "C" void kernel_launch(void* const* d_in, const int* in_sizes, int n_in,
                              void* d_out, int out_size, void* d_ws, size_t ws_size,
                              hipStream_t stream)
{
    const float* x    = (const float*)d_in[0];
    const float* flat = (const float*)d_in[1];
    const float* emb  = (const float*)d_in[2];
    const float* Wih  = (const float*)d_in[3];
    const float* Whh  = (const float*)d_in[4];
    const float* bih  = (const float*)d_in[5];
    const float* bhh  = (const float*)d_in[6];
    const float* fW   = (const float*)d_in[7];
    const float* fb   = (const float*)d_in[8];
    const float* s1Wl = (const float*)d_in[9];
    const float* s1Wr = (const float*)d_in[10];
    const float* s1b  = (const float*)d_in[11];
    const float* s2Wl = (const float*)d_in[12];
    const float* s2Wr = (const float*)d_in[13];
    const float* s2b  = (const float*)d_in[14];
    const float* oW   = (const float*)d_in[15];
    const float* ob   = (const float*)d_in[16];
    float* out = (float*)d_out;

    // workspace layout (floats). Zero zone first -> single memset.
    float* w     = (float*)d_ws;
    float* h0buf = w;                     // 57344  (NP*HD)  [zero: h0]
    float* agg1  = w + 57344;             // 70400  (NN*GIN) [zero]
    float* agg2  = w + 127744;            // 25600  (NN*GH)  [zero]
    float* cnt1  = w + 153344;            // 112            [zero]
    float* cnt2  = w + 153456;            // 112            [zero]
    int*   bar   = (int*)(w + 153568);    // 448 ints       [zero]
    float* h1buf = w + 154016;            // 57344
    float* gnn   = w + 211360;            // 70400
    float* h1    = w + 281760;            // 25600
    float* gbuf  = w + 307360;            // 12800
    float* mx    = w + 320160;            // 112
    int*   tgt   = (int*)(w + 320272);    // 800 ints
    // total: 321072 floats = ~1.23 MiB

    (void)hipMemsetAsync(d_ws, 0, 154016 * sizeof(float), stream);

    gru_kernel<<<GRPS * SLC, 256, 0, stream>>>(x, Wih, Whh, bih, bhh, h0buf, h1buf, bar);
    e1_gnn_in<<<NN, 128, 0, stream>>>(h0buf, flat, emb, fW, fb, gnn);
    e2a_norm<<<1, 128, 0, stream>>>(emb, mx);
    e2b_knn<<<NN, 128, 0, stream>>>(emb, mx, tgt);
    e3_agg<<<NN * KNN, 256, 0, stream>>>(gnn, tgt, agg1, cnt1, GIN);
    e4_sage<<<NN, GH, 2 * GIN * sizeof(float), stream>>>(agg1, gnn, cnt1, s1Wl, s1Wr, s1b, h1, GIN, GH, 1);
    e3_agg<<<NN * KNN, 256, 0, stream>>>(h1, tgt, agg2, cnt2, GH);
    e4_sage<<<NN, GOUT, 2 * GH * sizeof(float), stream>>>(agg2, h1, cnt2, s2Wl, s2Wr, s2b, gbuf, GH, GOUT, 0);
    e7_out<<<1, 128, 0, stream>>>(gbuf, h0buf, oW, ob, out);
}

// Round 2
// 25690.225 us; speedup vs baseline: 2.9943x; 2.9943x over previous
//
#include <hip/hip_runtime.h>
#include <math.h>

// ---------------- problem constants ----------------
#define TS   2048   // timesteps
#define NN   100    // nodes
#define FD   128    // input features
#define HD   512    // hidden
#define G3   1536   // 3*HD
#define NG   7      // node groups of 16
#define NS   16     // hidden slices (32 h-cols each)
#define KNN  8
#define GIN  704    // HD + 64 + 128
#define GH   256
#define GOUT 128

typedef float  f32x4  __attribute__((ext_vector_type(4)));
typedef __bf16 bf16x8 __attribute__((ext_vector_type(8)));
#define MFMA16(a, b, c) __builtin_amdgcn_mfma_f32_16x16x32_bf16((a), (b), (c), 0, 0, 0)

#define AST 648   // padded LDS row stride (bf16 elems): 4-bank shift/row, 16B aligned

__device__ __forceinline__ float sigmoidf_(float v) { return 1.f / (1.f + __expf(-v)); }
__device__ __forceinline__ float tanhf_(float v) {
    float ex = __expf(2.f * v);
    return 1.f - 2.f / (ex + 1.f);     // saturates correctly at +/-inf
}

// =====================================================================
// Persistent GRU. Grid = NG*NS = 112 blocks, 256 threads (4 waves).
// block (g,s): nodes [16g,16g+16), h-cols [32s,32s+32).
// Weights for this block's 96 gate rows (r/z/n x 32 cols) are converted
// to bf16 and parked in LDS ONCE. Per step: stage A=[x_t|h] (16x640 bf16)
// in LDS, 120 MFMA 16x16x32 (K split across wave pairs, LDS reduction),
// gate math fp32, write h (bf16) to ping-pong buffer, per-group
// device-scope barrier over the 16 slice-blocks.
// =====================================================================
__global__ __launch_bounds__(256, 1) void gru_kernel(
    const float* __restrict__ x,     // [TS, NN, FD]
    const float* __restrict__ Wih,   // [G3, FD]
    const float* __restrict__ Whh,   // [G3, HD]
    const float* __restrict__ bih,   // [G3]
    const float* __restrict__ bhh,   // [G3]
    __bf16* __restrict__ h0buf,      // [112, HD] bf16, zero-init (h0)
    __bf16* __restrict__ h1buf,      // [112, HD] bf16
    float*  __restrict__ enc,        // [112, HD] fp32, final h
    int*    __restrict__ bar)        // [NG][64] zero-init
{
    const int bid = blockIdx.x;
    const int g   = bid >> 4;        // node group
    const int s   = bid & 15;        // hidden slice
    const int tid = threadIdx.x;
    const int w   = tid >> 6;        // wave 0..3
    const int ln  = tid & 63;        // lane
    const int p   = w >> 1;          // pair -> col subtile (16 cols)
    const int role = w & 1;          // 0: K=[0,320)+nx, 1: K=[320,640)
    const int nb  = g * 16;

    __shared__ __align__(16) __bf16 Wlds[96][AST];   // 96 gate rows x 640
    __shared__ __align__(16) __bf16 Alds[16][AST];   // [x_t | h] 16 x 640
    __shared__ float Red[2][3][64][4];               // pair, gate, lane, reg

    // ---- one-time: park this block's weight rows in LDS (bf16) ----
    // LDS row r (0..95): gate = r/32 (r,z,n), col = 32*s + r%32
    for (int idx = tid; idx < 96 * 160; idx += 256) {
        int row = idx / 160;          // LDS row
        int c4  = idx % 160;          // float4 index within 640
        int grow = (row >> 5) * HD + 32 * s + (row & 31);
        float4 v;
        if (c4 < 32) v = ((const float4*)(Wih + (size_t)grow * FD))[c4];
        else         v = ((const float4*)(Whh + (size_t)grow * HD))[c4 - 32];
        __bf16* dst = &Wlds[row][c4 * 4];
        dst[0] = (__bf16)v.x; dst[1] = (__bf16)v.y;
        dst[2] = (__bf16)v.z; dst[3] = (__bf16)v.w;
    }

    // ---- per-lane constants ----
    const int mi   = ln & 15;            // A row (node) for frags / D col
    const int kq8  = (ln >> 4) * 8;      // K sub-offset within 32
    const int rowR = 16 * p;             // Wlds row bases for this subtile
    const int rowZ = 32 + 16 * p;
    const int rowN = 64 + 16 * p;
    const int ch   = 32 * s + 16 * p + (ln & 15);   // global h col (for gates)
    const float bR  = bih[ch] + bhh[ch];
    const float bZ  = bih[HD + ch] + bhh[HD + ch];
    const float bNX = bih[2 * HD + ch];
    const float bNH = bhh[2 * HD + ch];

    int* cntp  = bar + g * 64;
    int* flagp = bar + g * 64 + 32;

    __syncthreads();   // Wlds ready

    for (int t = 0; t < TS; ++t) {
        const __bf16* hcur = (t & 1) ? h1buf : h0buf;
        __bf16*       hnxt = (t & 1) ? h0buf : h1buf;

        // ---- stage A = [x_t | h] (16 x 640 bf16) ----
        {
            const float* xt = x + (size_t)t * NN * FD;
            #pragma unroll
            for (int q = 0; q < 2; ++q) {            // x: 16 rows x 32 float4
                int v   = tid + q * 256;
                int row = v >> 5;
                int fc  = (v & 31) << 2;
                float4 val = make_float4(0.f, 0.f, 0.f, 0.f);
                if (nb + row < NN)
                    val = *(const float4*)(xt + (size_t)(nb + row) * FD + fc);
                __bf16* dst = &Alds[row][fc];
                dst[0] = (__bf16)val.x; dst[1] = (__bf16)val.y;
                dst[2] = (__bf16)val.z; dst[3] = (__bf16)val.w;
            }
            #pragma unroll
            for (int q = 0; q < 4; ++q) {            // h: 16 rows x 64 chunks(8 bf16)
                int v   = tid + q * 256;
                int row = v >> 6;
                int kc  = (v & 63) << 3;
                bf16x8 val = *(const bf16x8*)(hcur + (size_t)(nb + row) * HD + kc);
                *(bf16x8*)&Alds[row][FD + kc] = val;
            }
        }
        __syncthreads();

        // ---- MFMA: gates for 16 nodes x 16 cols (subtile p), K split by role ----
        if (role == 0) {
            f32x4 aR = {0.f, 0.f, 0.f, 0.f}, aZ = aR, aNX = aR, aNH = aR;
            #pragma unroll
            for (int kk = 0; kk < 10; ++kk) {
                const int ko = 32 * kk + kq8;
                bf16x8 av = *(const bf16x8*)&Alds[mi][ko];
                aR = MFMA16(av, *(const bf16x8*)&Wlds[rowR + mi][ko], aR);
                aZ = MFMA16(av, *(const bf16x8*)&Wlds[rowZ + mi][ko], aZ);
                if (kk < 4) aNX = MFMA16(av, *(const bf16x8*)&Wlds[rowN + mi][ko], aNX);
                else        aNH = MFMA16(av, *(const bf16x8*)&Wlds[rowN + mi][ko], aNH);
            }
            __syncthreads();   // partner's Red ready after this
            // combine with partner partials, gates, h update
            #pragma unroll
            for (int e = 0; e < 4; ++e) {
                int   row = (ln >> 4) * 4 + e;         // node within group
                int   col = ln & 15;                   // == ch's low bits
                float rv = sigmoidf_(aR[e] + Red[p][0][ln][e] + bR);
                float zv = sigmoidf_(aZ[e] + Red[p][1][ln][e] + bZ);
                float nv = tanhf_(aNX[e] + bNX + rv * (aNH[e] + Red[p][2][ln][e] + bNH));
                float hold = (float)Alds[row][FD + 32 * s + 16 * p + col];
                float hnew = (1.f - zv) * nv + zv * hold;
                hnxt[(size_t)(nb + row) * HD + ch] = (__bf16)hnew;
                if (t == TS - 1 && nb + row < NN)
                    enc[(size_t)(nb + row) * HD + ch] = hnew;
            }
        } else {
            f32x4 aR = {0.f, 0.f, 0.f, 0.f}, aZ = aR, aNH = aR;
            #pragma unroll
            for (int kk = 10; kk < 20; ++kk) {
                const int ko = 32 * kk + kq8;
                bf16x8 av = *(const bf16x8*)&Alds[mi][ko];
                aR  = MFMA16(av, *(const bf16x8*)&Wlds[rowR + mi][ko], aR);
                aZ  = MFMA16(av, *(const bf16x8*)&Wlds[rowZ + mi][ko], aZ);
                aNH = MFMA16(av, *(const bf16x8*)&Wlds[rowN + mi][ko], aNH);
            }
            #pragma unroll
            for (int e = 0; e < 4; ++e) {
                Red[p][0][ln][e] = aR[e];
                Red[p][1][ln][e] = aZ[e];
                Red[p][2][ln][e] = aNH[e];
            }
            __syncthreads();
        }

        // ---- per-group barrier (device scope: h crosses XCDs) ----
        __syncthreads();
        if (tid == 0) {
            __threadfence();
            int old = __hip_atomic_fetch_add(cntp, 1, __ATOMIC_ACQ_REL, __HIP_MEMORY_SCOPE_AGENT);
            if (old == NS - 1) {
                __hip_atomic_store(cntp, 0, __ATOMIC_RELAXED, __HIP_MEMORY_SCOPE_AGENT);
                __hip_atomic_store(flagp, t + 1, __ATOMIC_RELEASE, __HIP_MEMORY_SCOPE_AGENT);
            } else {
                int f;
                do {
                    __builtin_amdgcn_s_sleep(1);
                    f = __hip_atomic_load(flagp, __ATOMIC_ACQUIRE, __HIP_MEMORY_SCOPE_AGENT);
                } while (f < t + 1);
            }
            __threadfence();
        }
        __syncthreads();
    }
}

// ===================== epilogue (tiny) =====================

__global__ void e1_gnn_in(const float* __restrict__ enc, const float* __restrict__ flat,
                          const float* __restrict__ emb, const float* __restrict__ fW,
                          const float* __restrict__ fb, float* __restrict__ gnn)
{
    int i = blockIdx.x, tid = threadIdx.x;
    const float4* src = (const float4*)(enc + (size_t)i * HD);
    float4* dst = (float4*)(gnn + (size_t)i * GIN);
    dst[tid] = src[tid];
    if (tid < 64) {
        float acc = fb[tid];
        const float* w  = fW + tid * 32;
        const float* fl = flat + i * 32;
        #pragma unroll
        for (int k = 0; k < 32; ++k) acc = fmaf(fl[k], w[k], acc);
        gnn[(size_t)i * GIN + HD + tid] = acc;
    }
    gnn[(size_t)i * GIN + HD + 64 + tid] = emb[(size_t)i * FD + tid];
}

__global__ void e2a_norm(const float* __restrict__ emb, float* __restrict__ mx)
{
    int j = threadIdx.x;
    if (j < NN) {
        float acc = 0.f;
        const float* e = emb + (size_t)j * FD;
        for (int d = 0; d < FD; ++d) acc = fmaf(e[d], e[d], acc);
        mx[j] = fmaxf(sqrtf(acc), 1e-8f);
    }
}

__global__ void e2b_knn(const float* __restrict__ emb, const float* __restrict__ mx,
                        int* __restrict__ tgt)
{
    int i = blockIdx.x, tid = threadIdx.x;   // 128 threads
    __shared__ float ei[FD];
    __shared__ float srow[NN];
    ei[tid] = emb[(size_t)i * FD + tid];
    __syncthreads();
    if (tid < NN) {
        float acc = 0.f;
        const float* e = emb + (size_t)tid * FD;
        for (int d = 0; d < FD; ++d) acc = fmaf(ei[d], e[d], acc);
        float sim = acc / (mx[i] * mx[tid]);
        srow[tid] = (tid == i) ? 0.f : sim;
    }
    __syncthreads();
    if (tid == 0) {
        for (int t = 0; t < KNN; ++t) {
            float best = -1e30f; int bi = 0;
            for (int j = 0; j < NN; ++j) { float v = srow[j]; if (v > best) { best = v; bi = j; } }
            srow[bi] = -1e30f;
            tgt[i * KNN + t] = bi;
        }
    }
}

__global__ void e3_agg(const float* __restrict__ xin, const int* __restrict__ tgt,
                       float* __restrict__ agg, float* __restrict__ cnt, int D)
{
    int e = blockIdx.x, src = e >> 3, tg = tgt[e];
    for (int d = threadIdx.x; d < D; d += blockDim.x)
        atomicAdd(&agg[(size_t)tg * D + d], xin[(size_t)src * D + d]);
    if (threadIdx.x == 0) atomicAdd(&cnt[tg], 1.0f);
}

__global__ void e4_sage(const float* __restrict__ agg, const float* __restrict__ xin,
                        const float* __restrict__ cnt,
                        const float* __restrict__ Wl, const float* __restrict__ Wr,
                        const float* __restrict__ b, float* __restrict__ out,
                        int Din, int Dout, int dorelu)
{
    int j = blockIdx.x, o = threadIdx.x;
    extern __shared__ float sm[];
    float* la = sm;
    float* lx = sm + Din;
    for (int d = o; d < Din; d += blockDim.x) {
        la[d] = agg[(size_t)j * Din + d];
        lx[d] = xin[(size_t)j * Din + d];
    }
    __syncthreads();
    float inv = 1.f / fmaxf(cnt[j], 1.f);
    float acc1 = 0.f, acc2 = 0.f;
    const float* wl = Wl + (size_t)o * Din;
    const float* wr = Wr + (size_t)o * Din;
    for (int k = 0; k < Din; ++k) {
        acc1 = fmaf(la[k], wl[k], acc1);
        acc2 = fmaf(lx[k], wr[k], acc2);
    }
    float v = fmaf(acc1, inv, acc2) + b[o];
    if (dorelu) v = fmaxf(v, 0.f);
    out[(size_t)j * Dout + o] = v;
}

__global__ void e7_out(const float* __restrict__ g, const float* __restrict__ enc,
                       const float* __restrict__ oW, const float* __restrict__ ob,
                       float* __restrict__ out)
{
    int j = threadIdx.x;
    if (j < NN) {
        float acc = ob[0];
        const float* gr = g + (size_t)j * GOUT;
        for (int d = 0; d < GOUT; ++d) acc = fmaf(gr[d], oW[d], acc);
        const float* er = enc + (size_t)j * HD;
        for (int d = 0; d < HD; ++d) acc = fmaf(er[d], oW[GOUT + d], acc);
        out[j] = 1.f / (1.f + expf(-acc));
    }
}

// ===================== launch =====================
extern "C" void kernel_launch(void* const* d_in, const int* in_sizes, int n_in,
                              void* d_out, int out_size, void* d_ws, size_t ws_size,
                              hipStream_t stream)
{
    const float* x    = (const float*)d_in[0];
    const float* flat = (const float*)d_in[1];
    const float* emb  = (const float*)d_in[2];
    const float* Wih  = (const float*)d_in[3];
    const float* Whh  = (const float*)d_in[4];
    const float* bih  = (const float*)d_in[5];
    const float* bhh  = (const float*)d_in[6];
    const float* fW   = (const float*)d_in[7];
    const float* fb   = (const float*)d_in[8];
    const float* s1Wl = (const float*)d_in[9];
    const float* s1Wr = (const float*)d_in[10];
    const float* s1b  = (const float*)d_in[11];
    const float* s2Wl = (const float*)d_in[12];
    const float* s2Wr = (const float*)d_in[13];
    const float* s2b  = (const float*)d_in[14];
    const float* oW   = (const float*)d_in[15];
    const float* ob   = (const float*)d_in[16];
    float* out = (float*)d_out;

    // workspace layout (bytes). Zero zone first -> single memset.
    char* p = (char*)d_ws;
    __bf16* h0buf = (__bf16*)(p + 0);        // 114688  [zero: h0]
    float*  agg1  = (float*)(p + 114688);    // 281600  [zero]
    float*  agg2  = (float*)(p + 396288);    // 102400  [zero]
    float*  cnt1  = (float*)(p + 498688);    // 448     [zero]
    float*  cnt2  = (float*)(p + 499136);    // 448     [zero]
    int*    bar   = (int*)  (p + 499584);    // 1792    [zero]
    __bf16* h1buf = (__bf16*)(p + 501376);   // 114688
    float*  enc   = (float*)(p + 616064);    // 229376
    float*  gnn   = (float*)(p + 845440);    // 281600
    float*  h1s   = (float*)(p + 1127040);   // 102400
    float*  gbuf  = (float*)(p + 1229440);   // 51200
    float*  mx    = (float*)(p + 1280640);   // 448
    int*    tgt   = (int*)  (p + 1281088);   // 3200
    // total ~1.23 MiB

    (void)hipMemsetAsync(d_ws, 0, 501376, stream);

    gru_kernel<<<NG * NS, 256, 0, stream>>>(x, Wih, Whh, bih, bhh, h0buf, h1buf, enc, bar);
    e1_gnn_in<<<NN, 128, 0, stream>>>(enc, flat, emb, fW, fb, gnn);
    e2a_norm<<<1, 128, 0, stream>>>(emb, mx);
    e2b_knn<<<NN, 128, 0, stream>>>(emb, mx, tgt);
    e3_agg<<<NN * KNN, 256, 0, stream>>>(gnn, tgt, agg1, cnt1, GIN);
    e4_sage<<<NN, GH, 2 * GIN * sizeof(float), stream>>>(agg1, gnn, cnt1, s1Wl, s1Wr, s1b, h1s, GIN, GH, 1);
    e3_agg<<<NN * KNN, 256, 0, stream>>>(h1s, tgt, agg2, cnt2, GH);
    e4_sage<<<NN, GOUT, 2 * GH * sizeof(float), stream>>>(agg2, h1s, cnt2, s2Wl, s2Wr, s2b, gbuf, GH, GOUT, 0);
    e7_out<<<1, 128, 0, stream>>>(gbuf, enc, oW, ob, out);
}

// Round 3
// 12149.536 us; speedup vs baseline: 6.3316x; 2.1145x over previous
//
#include <hip/hip_runtime.h>
#include <math.h>

// ---------------- problem constants ----------------
#define TS   2048   // timesteps
#define NN   100    // nodes
#define FD   128    // input features
#define HD   512    // hidden
#define G3   1536   // 3*HD
#define NG   7      // node groups of 16
#define NS   16     // hidden slices (32 h-cols each)
#define KNN  8
#define GIN  704    // HD + 64 + 128
#define GH   256
#define GOUT 128

typedef float  f32x4  __attribute__((ext_vector_type(4)));
typedef __bf16 bf16x8 __attribute__((ext_vector_type(8)));
typedef __bf16 bf16x4 __attribute__((ext_vector_type(4)));
#define MFMA16(a, b, c) __builtin_amdgcn_mfma_f32_16x16x32_bf16((a), (b), (c), 0, 0, 0)

#define AST 648   // padded LDS row stride (bf16 elems)

__device__ __forceinline__ float sigmoidf_(float v) { return 1.f / (1.f + __expf(-v)); }
__device__ __forceinline__ float tanhf_(float v) {
    float ex = __expf(2.f * v);
    return 1.f - 2.f / (ex + 1.f);
}

// coherent (LLC-routed) 8-byte accesses: relaxed agent-scope atomics.
// These bypass the non-coherent per-XCD L1/L2 -> no cache fences needed.
__device__ __forceinline__ unsigned long long cload(const unsigned long long* p) {
    return __hip_atomic_load(p, __ATOMIC_RELAXED, __HIP_MEMORY_SCOPE_AGENT);
}
__device__ __forceinline__ void cstore(unsigned long long* p, unsigned long long v) {
    __hip_atomic_store(p, v, __ATOMIC_RELAXED, __HIP_MEMORY_SCOPE_AGENT);
}

// =====================================================================
// Persistent GRU. Grid = NG*NS = 112 blocks, 256 threads (4 waves).
// block (g,s): nodes [16g,16g+16), h-cols [32s,32s+32).
// Weights (96 gate rows x 640, bf16) parked in LDS once. Per step:
// stage A=[x_t|h] in LDS (h via coherent uint64 loads), 120 MFMA
// 16x16x32 split across wave pairs w/ LDS reduction, gate math fp32,
// h written back via coherent packed stores, then a fence-free
// monotone-counter barrier over the group's 16 blocks.
// =====================================================================
__global__ __launch_bounds__(256, 1) void gru_kernel(
    const float* __restrict__ x,     // [TS, NN, FD]
    const float* __restrict__ Wih,   // [G3, FD]
    const float* __restrict__ Whh,   // [G3, HD]
    const float* __restrict__ bih,   // [G3]
    const float* __restrict__ bhh,   // [G3]
    __bf16* __restrict__ h0buf,      // [112, HD] bf16, zero-init (h0)
    __bf16* __restrict__ h1buf,      // [112, HD] bf16
    float*  __restrict__ enc,        // [112, HD] fp32, final h
    int*    __restrict__ bar)        // [NG][64] zero-init
{
    const int bid = blockIdx.x;
    const int g   = bid >> 4;        // node group
    const int s   = bid & 15;        // hidden slice
    const int tid = threadIdx.x;
    const int w   = tid >> 6;        // wave 0..3
    const int ln  = tid & 63;        // lane
    const int p   = w >> 1;          // pair -> col subtile (16 cols)
    const int role = w & 1;          // 0: K=[0,320)+nx, 1: K=[320,640)
    const int nb  = g * 16;

    __shared__ __align__(16) __bf16 Wlds[96][AST];   // 96 gate rows x 640
    __shared__ __align__(16) __bf16 Alds[16][AST];   // [x_t | h] 16 x 640
    __shared__ float  Red[2][3][64][4];              // pair, gate, lane, reg
    __shared__ __align__(8) __bf16 Hnew[16][40];     // new h tile (32 cols + pad)

    // ---- one-time: park this block's weight rows in LDS (bf16) ----
    for (int idx = tid; idx < 96 * 160; idx += 256) {
        int row = idx / 160;
        int c4  = idx % 160;
        int grow = (row >> 5) * HD + 32 * s + (row & 31);
        float4 v;
        if (c4 < 32) v = ((const float4*)(Wih + (size_t)grow * FD))[c4];
        else         v = ((const float4*)(Whh + (size_t)grow * HD))[c4 - 32];
        __bf16* dst = &Wlds[row][c4 * 4];
        dst[0] = (__bf16)v.x; dst[1] = (__bf16)v.y;
        dst[2] = (__bf16)v.z; dst[3] = (__bf16)v.w;
    }

    // ---- per-lane constants ----
    const int mi   = ln & 15;
    const int kq8  = (ln >> 4) * 8;
    const int rowR = 16 * p;
    const int rowZ = 32 + 16 * p;
    const int rowN = 64 + 16 * p;
    const int ch   = 32 * s + 16 * p + (ln & 15);
    const float bR  = bih[ch] + bhh[ch];
    const float bZ  = bih[HD + ch] + bhh[HD + ch];
    const float bNX = bih[2 * HD + ch];
    const float bNH = bhh[2 * HD + ch];

    int* cntp  = bar + g * 64;        // monotone accumulating counter
    int* flagp = bar + g * 64 + 32;   // last completed step + 1

    __syncthreads();   // Wlds ready

    for (int t = 0; t < TS; ++t) {
        const __bf16* hcur = (t & 1) ? h1buf : h0buf;
        __bf16*       hnxt = (t & 1) ? h0buf : h1buf;

        // ---- stage A = [x_t | h] (16 x 640 bf16) ----
        {
            const float* xt = x + (size_t)t * NN * FD;
            #pragma unroll
            for (int q = 0; q < 2; ++q) {            // x: 16 rows x 32 float4
                int v   = tid + q * 256;
                int row = v >> 5;
                int fc  = (v & 31) << 2;
                float4 val = make_float4(0.f, 0.f, 0.f, 0.f);
                if (nb + row < NN)
                    val = *(const float4*)(xt + (size_t)(nb + row) * FD + fc);
                __bf16* dst = &Alds[row][fc];
                dst[0] = (__bf16)val.x; dst[1] = (__bf16)val.y;
                dst[2] = (__bf16)val.z; dst[3] = (__bf16)val.w;
            }
            #pragma unroll
            for (int q = 0; q < 8; ++q) {            // h: 16 rows x 128 u64 (4 bf16 each)
                int v   = tid + q * 256;             // 0..2047
                int row = v >> 7;
                int c4  = (v & 127) << 2;            // col (bf16 units), 8B-aligned
                unsigned long long hv =
                    cload((const unsigned long long*)(hcur + (size_t)(nb + row) * HD + c4));
                *(unsigned long long*)&Alds[row][FD + c4] = hv;
            }
        }
        __syncthreads();

        // ---- MFMA: 16 nodes x 16 cols (subtile p), K split by role ----
        if (role == 0) {
            f32x4 aR = {0.f, 0.f, 0.f, 0.f}, aZ = aR, aNX = aR, aNH = aR;
            #pragma unroll
            for (int kk = 0; kk < 10; ++kk) {
                const int ko = 32 * kk + kq8;
                bf16x8 av = *(const bf16x8*)&Alds[mi][ko];
                aR = MFMA16(av, *(const bf16x8*)&Wlds[rowR + mi][ko], aR);
                aZ = MFMA16(av, *(const bf16x8*)&Wlds[rowZ + mi][ko], aZ);
                if (kk < 4) aNX = MFMA16(av, *(const bf16x8*)&Wlds[rowN + mi][ko], aNX);
                else        aNH = MFMA16(av, *(const bf16x8*)&Wlds[rowN + mi][ko], aNH);
            }
            __syncthreads();   // partner's Red ready
            #pragma unroll
            for (int e = 0; e < 4; ++e) {
                int   row = (ln >> 4) * 4 + e;
                int   col = ln & 15;
                float rv = sigmoidf_(aR[e] + Red[p][0][ln][e] + bR);
                float zv = sigmoidf_(aZ[e] + Red[p][1][ln][e] + bZ);
                float nv = tanhf_(aNX[e] + bNX + rv * (aNH[e] + Red[p][2][ln][e] + bNH));
                float hold = (float)Alds[row][FD + 32 * s + 16 * p + col];
                float hnew = (1.f - zv) * nv + zv * hold;
                Hnew[row][16 * p + col] = (__bf16)hnew;
                if (t == TS - 1 && nb + row < NN)
                    enc[(size_t)(nb + row) * HD + ch] = hnew;
            }
        } else {
            f32x4 aR = {0.f, 0.f, 0.f, 0.f}, aZ = aR, aNH = aR;
            #pragma unroll
            for (int kk = 10; kk < 20; ++kk) {
                const int ko = 32 * kk + kq8;
                bf16x8 av = *(const bf16x8*)&Alds[mi][ko];
                aR  = MFMA16(av, *(const bf16x8*)&Wlds[rowR + mi][ko], aR);
                aZ  = MFMA16(av, *(const bf16x8*)&Wlds[rowZ + mi][ko], aZ);
                aNH = MFMA16(av, *(const bf16x8*)&Wlds[rowN + mi][ko], aNH);
            }
            #pragma unroll
            for (int e = 0; e < 4; ++e) {
                Red[p][0][ln][e] = aR[e];
                Red[p][1][ln][e] = aZ[e];
                Red[p][2][ln][e] = aNH[e];
            }
            __syncthreads();
        }
        __syncthreads();   // Hnew complete

        // ---- publish h: packed coherent stores (16 rows x 32 cols) ----
        if (tid < 128) {
            int row = tid >> 3;
            int c4  = (tid & 7) << 2;        // col within slice, 4 bf16
            unsigned long long hv = *(const unsigned long long*)&Hnew[row][c4];
            cstore((unsigned long long*)(hnxt + (size_t)(nb + row) * HD + 32 * s + c4), hv);
        }
        asm volatile("s_waitcnt vmcnt(0)" ::: "memory");   // h acked at LLC
        __syncthreads();

        // ---- fence-free barrier: monotone counter + step flag ----
        if (tid == 0) {
            int old = __hip_atomic_fetch_add(cntp, 1, __ATOMIC_RELAXED, __HIP_MEMORY_SCOPE_AGENT);
            if (old == (t + 1) * NS - 1) {
                __hip_atomic_store(flagp, t + 1, __ATOMIC_RELAXED, __HIP_MEMORY_SCOPE_AGENT);
            } else {
                int f;
                do {
                    __builtin_amdgcn_s_sleep(1);
                    f = __hip_atomic_load(flagp, __ATOMIC_RELAXED, __HIP_MEMORY_SCOPE_AGENT);
                } while (f < t + 1);
            }
        }
        __syncthreads();
    }
}

// ===================== epilogue (tiny) =====================

__global__ void e1_gnn_in(const float* __restrict__ enc, const float* __restrict__ flat,
                          const float* __restrict__ emb, const float* __restrict__ fW,
                          const float* __restrict__ fb, float* __restrict__ gnn)
{
    int i = blockIdx.x, tid = threadIdx.x;
    const float4* src = (const float4*)(enc + (size_t)i * HD);
    float4* dst = (float4*)(gnn + (size_t)i * GIN);
    dst[tid] = src[tid];
    if (tid < 64) {
        float acc = fb[tid];
        const float* w  = fW + tid * 32;
        const float* fl = flat + i * 32;
        #pragma unroll
        for (int k = 0; k < 32; ++k) acc = fmaf(fl[k], w[k], acc);
        gnn[(size_t)i * GIN + HD + tid] = acc;
    }
    gnn[(size_t)i * GIN + HD + 64 + tid] = emb[(size_t)i * FD + tid];
}

__global__ void e2a_norm(const float* __restrict__ emb, float* __restrict__ mx)
{
    int j = threadIdx.x;
    if (j < NN) {
        float acc = 0.f;
        const float* e = emb + (size_t)j * FD;
        for (int d = 0; d < FD; ++d) acc = fmaf(e[d], e[d], acc);
        mx[j] = fmaxf(sqrtf(acc), 1e-8f);
    }
}

__global__ void e2b_knn(const float* __restrict__ emb, const float* __restrict__ mx,
                        int* __restrict__ tgt)
{
    int i = blockIdx.x, tid = threadIdx.x;   // 128 threads
    __shared__ float ei[FD];
    __shared__ float srow[NN];
    ei[tid] = emb[(size_t)i * FD + tid];
    __syncthreads();
    if (tid < NN) {
        float acc = 0.f;
        const float* e = emb + (size_t)tid * FD;
        for (int d = 0; d < FD; ++d) acc = fmaf(ei[d], e[d], acc);
        float sim = acc / (mx[i] * mx[tid]);
        srow[tid] = (tid == i) ? 0.f : sim;
    }
    __syncthreads();
    if (tid == 0) {
        for (int t = 0; t < KNN; ++t) {
            float best = -1e30f; int bi = 0;
            for (int j = 0; j < NN; ++j) { float v = srow[j]; if (v > best) { best = v; bi = j; } }
            srow[bi] = -1e30f;
            tgt[i * KNN + t] = bi;
        }
    }
}

__global__ void e3_agg(const float* __restrict__ xin, const int* __restrict__ tgt,
                       float* __restrict__ agg, float* __restrict__ cnt, int D)
{
    int e = blockIdx.x, src = e >> 3, tg = tgt[e];
    for (int d = threadIdx.x; d < D; d += blockDim.x)
        atomicAdd(&agg[(size_t)tg * D + d], xin[(size_t)src * D + d]);
    if (threadIdx.x == 0) atomicAdd(&cnt[tg], 1.0f);
}

__global__ void e4_sage(const float* __restrict__ agg, const float* __restrict__ xin,
                        const float* __restrict__ cnt,
                        const float* __restrict__ Wl, const float* __restrict__ Wr,
                        const float* __restrict__ b, float* __restrict__ out,
                        int Din, int Dout, int dorelu)
{
    int j = blockIdx.x, o = threadIdx.x;
    extern __shared__ float sm[];
    float* la = sm;
    float* lx = sm + Din;
    for (int d = o; d < Din; d += blockDim.x) {
        la[d] = agg[(size_t)j * Din + d];
        lx[d] = xin[(size_t)j * Din + d];
    }
    __syncthreads();
    float inv = 1.f / fmaxf(cnt[j], 1.f);
    float acc1 = 0.f, acc2 = 0.f;
    const float* wl = Wl + (size_t)o * Din;
    const float* wr = Wr + (size_t)o * Din;
    for (int k = 0; k < Din; ++k) {
        acc1 = fmaf(la[k], wl[k], acc1);
        acc2 = fmaf(lx[k], wr[k], acc2);
    }
    float v = fmaf(acc1, inv, acc2) + b[o];
    if (dorelu) v = fmaxf(v, 0.f);
    out[(size_t)j * Dout + o] = v;
}

__global__ void e7_out(const float* __restrict__ g, const float* __restrict__ enc,
                       const float* __restrict__ oW, const float* __restrict__ ob,
                       float* __restrict__ out)
{
    int j = threadIdx.x;
    if (j < NN) {
        float acc = ob[0];
        const float* gr = g + (size_t)j * GOUT;
        for (int d = 0; d < GOUT; ++d) acc = fmaf(gr[d], oW[d], acc);
        const float* er = enc + (size_t)j * HD;
        for (int d = 0; d < HD; ++d) acc = fmaf(er[d], oW[GOUT + d], acc);
        out[j] = 1.f / (1.f + expf(-acc));
    }
}

// ===================== launch =====================
extern "C" void kernel_launch(void* const* d_in, const int* in_sizes, int n_in,
                              void* d_out, int out_size, void* d_ws, size_t ws_size,
                              hipStream_t stream)
{
    const float* x    = (const float*)d_in[0];
    const float* flat = (const float*)d_in[1];
    const float* emb  = (const float*)d_in[2];
    const float* Wih  = (const float*)d_in[3];
    const float* Whh  = (const float*)d_in[4];
    const float* bih  = (const float*)d_in[5];
    const float* bhh  = (const float*)d_in[6];
    const float* fW   = (const float*)d_in[7];
    const float* fb   = (const float*)d_in[8];
    const float* s1Wl = (const float*)d_in[9];
    const float* s1Wr = (const float*)d_in[10];
    const float* s1b  = (const float*)d_in[11];
    const float* s2Wl = (const float*)d_in[12];
    const float* s2Wr = (const float*)d_in[13];
    const float* s2b  = (const float*)d_in[14];
    const float* oW   = (const float*)d_in[15];
    const float* ob   = (const float*)d_in[16];
    float* out = (float*)d_out;

    // workspace layout (bytes). Zero zone first -> single memset.
    char* p = (char*)d_ws;
    __bf16* h0buf = (__bf16*)(p + 0);        // 114688  [zero: h0]
    float*  agg1  = (float*)(p + 114688);    // 281600  [zero]
    float*  agg2  = (float*)(p + 396288);    // 102400  [zero]
    float*  cnt1  = (float*)(p + 498688);    // 448     [zero]
    float*  cnt2  = (float*)(p + 499136);    // 448     [zero]
    int*    bar   = (int*)  (p + 499584);    // 1792    [zero]
    __bf16* h1buf = (__bf16*)(p + 501376);   // 114688
    float*  enc   = (float*)(p + 616064);    // 229376
    float*  gnn   = (float*)(p + 845440);    // 281600
    float*  h1s   = (float*)(p + 1127040);   // 102400
    float*  gbuf  = (float*)(p + 1229440);   // 51200
    float*  mx    = (float*)(p + 1280640);   // 448
    int*    tgt   = (int*)  (p + 1281088);   // 3200

    (void)hipMemsetAsync(d_ws, 0, 501376, stream);

    gru_kernel<<<NG * NS, 256, 0, stream>>>(x, Wih, Whh, bih, bhh, h0buf, h1buf, enc, bar);
    e1_gnn_in<<<NN, 128, 0, stream>>>(enc, flat, emb, fW, fb, gnn);
    e2a_norm<<<1, 128, 0, stream>>>(emb, mx);
    e2b_knn<<<NN, 128, 0, stream>>>(emb, mx, tgt);
    e3_agg<<<NN * KNN, 256, 0, stream>>>(gnn, tgt, agg1, cnt1, GIN);
    e4_sage<<<NN, GH, 2 * GIN * sizeof(float), stream>>>(agg1, gnn, cnt1, s1Wl, s1Wr, s1b, h1s, GIN, GH, 1);
    e3_agg<<<NN * KNN, 256, 0, stream>>>(h1s, tgt, agg2, cnt2, GH);
    e4_sage<<<NN, GOUT, 2 * GH * sizeof(float), stream>>>(agg2, h1s, cnt2, s2Wl, s2Wr, s2b, gbuf, GH, GOUT, 0);
    e7_out<<<1, 128, 0, stream>>>(gbuf, enc, oW, ob, out);
}